// Round 14
// baseline (605.420 us; speedup 1.0000x reference)
//
#include <hip/hip_runtime.h>
#include <math.h>

constexpr int Lseq = 4096, Dm = 1024, H = 4, DK = 512, DV = 1024;
constexpr int DQH = 128, DVH = 256, CH = 64, ROWS = 4 * 4096;

typedef unsigned short u16;
struct alignas(16) us8 { u16 u[8]; };
typedef __attribute__((ext_vector_type(8))) short bf16x8;   // 8 bf16 (4 VGPRs)
typedef __attribute__((ext_vector_type(4))) float f32x4;

__device__ __forceinline__ float sig_(float x) { return 1.f / (1.f + expf(-x)); }
__device__ __forceinline__ float b2f(u16 u) {
  union { float f; unsigned v; } x; x.v = (unsigned)u << 16; return x.f;
}
__device__ __forceinline__ u16 f2b(float f) {   // round-to-nearest-even
  union { float f; unsigned v; } x; x.f = f;
  unsigned r = x.v + 0x7fffu + ((x.v >> 16) & 1u);
  return (u16)(r >> 16);
}
// async global->LDS, 16B per lane; lds dest = wave-uniform base + lane*16
__device__ __forceinline__ void gld16(const u16* g, u16* l) {
  __builtin_amdgcn_global_load_lds(
      (const __attribute__((address_space(1))) void*)g,
      (__attribute__((address_space(3))) void*)l, 16, 0, 0);
}
// LDS-only barrier: drains LDS ops, lets global loads/stores stay in flight
// (T4: avoids the compiler's s_waitcnt vmcnt(0) before s_barrier).
__device__ __forceinline__ void lds_barrier() {
  asm volatile("s_waitcnt lgkmcnt(0)" ::: "memory");
  __builtin_amdgcn_s_barrier();
  asm volatile("" ::: "memory");
}

__global__ void ws_sentinel_kernel(float* out, float v) { out[0] = v; }

// ---- 0. f32 -> bf16 convert + TRANSPOSE: in[K][N] -> out[N][K] ----
__global__ __launch_bounds__(256) void cvt_t_kernel(
    const float* __restrict__ in, u16* __restrict__ out, int N, int K) {
  __shared__ u16 T[32][66];
  const int k0 = blockIdx.y * 32, n0 = blockIdx.x * 64;
  const int t = threadIdx.x;
#pragma unroll
  for (int i = 0; i < 8; ++i) {
    int idx = t + i * 256;
    int kk = idx >> 6, nn = idx & 63;
    T[kk][nn] = f2b(in[(size_t)(k0 + kk) * N + n0 + nn]);
  }
  __syncthreads();
#pragma unroll
  for (int i = 0; i < 8; ++i) {
    int idx = t + i * 256;
    int kk = idx & 31, nn = idx >> 5;
    out[(size_t)(n0 + nn) * K + k0 + kk] = T[kk][nn];
  }
}

// ---- 1. conv + silu -> bf16 ----
__global__ __launch_bounds__(256) void conv_silu_kernel(
    const float* __restrict__ x, const float* __restrict__ w, u16* __restrict__ h) {
  int idx = blockIdx.x * 256 + threadIdx.x;
  int d = idx & (Dm - 1), l = (idx >> 10) & (Lseq - 1), b = idx >> 22;
  const float* xb = x + ((size_t)b << 22);
  float acc = 0.f;
#pragma unroll
  for (int i = 0; i < 4; ++i) {
    int li = l - 3 + i;
    if (li >= 0) acc = fmaf(w[d * 4 + i], xb[((size_t)li << 10) | d], acc);
  }
  h[idx] = f2b(acc * sig_(acc));
}

// ---- 2. MFMA GEMM, m97 structure. MODE: 0=bf16 out, 1=f32 out, 2=bf16+l2norm
// (keeps __syncthreads: global_load_lds staging REQUIRES the vmcnt drain)
template <int MODE>
__global__ __launch_bounds__(256) void gemm_mfma_kernel(
    const u16* __restrict__ A, const u16* __restrict__ BT, void* __restrict__ Cv,
    int M, int N, int K) {
  __shared__ u16 As[128 * 32];
  __shared__ u16 Bs[128 * 32];
  const int tid = threadIdx.x;
  const int wid = tid >> 6, lane = tid & 63;
  const int wr = wid >> 1, wc = wid & 1;
  const int fr = lane & 15, fk = lane >> 4;
  const int nbx = N >> 7;
  const int bid = blockIdx.x, nwg = gridDim.x;
  const int swz = (bid & 7) * (nwg >> 3) + (bid >> 3);   // T1: nwg % 8 == 0
  const int row0 = (swz / nbx) * 128, col0 = (swz % nbx) * 128;

  const int sA[2] = {(0 * 4 + wid) * 64 + lane, (1 * 4 + wid) * 64 + lane};

  f32x4 acc[4][4];
#pragma unroll
  for (int i = 0; i < 4; ++i)
#pragma unroll
    for (int j = 0; j < 4; ++j) acc[i][j] = {0.f, 0.f, 0.f, 0.f};

  for (int k0 = 0; k0 < K; k0 += 32) {
#pragma unroll
    for (int i = 0; i < 2; ++i) {
      const int seg = sA[i];
      const int r = seg >> 2, k8 = (seg & 3) << 3;
      gld16(&A[(size_t)(row0 + r) * K + k0 + k8], &As[(i * 4 + wid) * 512]);
      gld16(&BT[(size_t)(col0 + r) * K + k0 + k8], &Bs[(i * 4 + wid) * 512]);
    }
    __syncthreads();
    bf16x8 af[4], bf[4];
#pragma unroll
    for (int mi = 0; mi < 4; ++mi)
      af[mi] = *(const bf16x8*)&As[(wr * 64 + mi * 16 + fr) * 32 + fk * 8];
#pragma unroll
    for (int ni = 0; ni < 4; ++ni)
      bf[ni] = *(const bf16x8*)&Bs[(wc * 64 + ni * 16 + fr) * 32 + fk * 8];
#pragma unroll
    for (int mi = 0; mi < 4; ++mi)
#pragma unroll
      for (int ni = 0; ni < 4; ++ni)
        acc[mi][ni] = __builtin_amdgcn_mfma_f32_16x16x32_bf16(
            af[mi], bf[ni], acc[mi][ni], 0, 0, 0);
    __syncthreads();
  }

  if (MODE == 2) {   // fused per-row l2norm over this block's 128 cols (one head)
    __shared__ float ssh[2][128];
#pragma unroll
    for (int mi = 0; mi < 4; ++mi)
#pragma unroll
      for (int r = 0; r < 4; ++r) {
        float p = 0.f;
#pragma unroll
        for (int ni = 0; ni < 4; ++ni) p += acc[mi][ni][r] * acc[mi][ni][r];
        p += __shfl_xor(p, 1); p += __shfl_xor(p, 2);
        p += __shfl_xor(p, 4); p += __shfl_xor(p, 8);
        if (fr == 0) ssh[wc][wr * 64 + mi * 16 + fk * 4 + r] = p;
      }
    __syncthreads();
#pragma unroll
    for (int mi = 0; mi < 4; ++mi)
#pragma unroll
      for (int r = 0; r < 4; ++r) {
        int ridx = wr * 64 + mi * 16 + fk * 4 + r;
        float sc = 1.f / fmaxf(sqrtf(ssh[0][ridx] + ssh[1][ridx]), 1e-12f);
#pragma unroll
        for (int ni = 0; ni < 4; ++ni) acc[mi][ni][r] *= sc;
      }
  }

  // epilogue: D col = lane&15, row = (lane>>4)*4 + r  [m89/m91-verified]
#pragma unroll
  for (int mi = 0; mi < 4; ++mi)
#pragma unroll
    for (int ni = 0; ni < 4; ++ni) {
      int col = col0 + wc * 64 + ni * 16 + fr;
#pragma unroll
      for (int r = 0; r < 4; ++r) {
        int row = row0 + wr * 64 + mi * 16 + fk * 4 + r;
        if (MODE == 1) ((float*)Cv)[(size_t)row * N + col] = acc[mi][ni][r];
        else           ((u16*)Cv)[(size_t)row * N + col] = f2b(acc[mi][ni][r]);
      }
    }
}

// ---- 3. beta ----
__global__ __launch_bounds__(256) void beta_kernel(
    const u16* __restrict__ h, const float* __restrict__ Wb, float* __restrict__ beta) {
  int row = blockIdx.x * 4 + (threadIdx.x >> 6), lane = threadIdx.x & 63;
  const u16* hrow = h + (size_t)row * Dm;
  float a0 = 0, a1 = 0, a2 = 0, a3 = 0;
  for (int k0 = 0; k0 < Dm; k0 += 64) {
    float hv = b2f(hrow[k0 + lane]);
    float4 wv = *(const float4*)&Wb[(size_t)(k0 + lane) * 4];
    a0 = fmaf(hv, wv.x, a0); a1 = fmaf(hv, wv.y, a1);
    a2 = fmaf(hv, wv.z, a2); a3 = fmaf(hv, wv.w, a3);
  }
#pragma unroll
  for (int off = 32; off; off >>= 1) {
    a0 += __shfl_down(a0, off); a1 += __shfl_down(a1, off);
    a2 += __shfl_down(a2, off); a3 += __shfl_down(a3, off);
  }
  if (lane == 0) {
    int b = row >> 12, l = row & (Lseq - 1);
    beta[((size_t)(b * H + 0)) * Lseq + l] = sig_(a0);
    beta[((size_t)(b * H + 1)) * Lseq + l] = sig_(a1);
    beta[((size_t)(b * H + 2)) * Lseq + l] = sig_(a2);
    beta[((size_t)(b * H + 3)) * Lseq + l] = sig_(a3);
  }
}

// ---- 5a. delta prep (LDS-only barriers) ----
__global__ __launch_bounds__(256) void delta_prep_kernel(
    const u16* __restrict__ q, const u16* __restrict__ k,
    u16* v, const float* __restrict__ beta,
    u16* __restrict__ Wout, u16* __restrict__ QKout) {
  __shared__ alignas(16) float Am[64][68];
  __shared__ alignas(16) float R[64][68];
  __shared__ float Bc[64];
  const int tid = threadIdx.x;
  const int wid = tid >> 6, lane = tid & 63;
  const int fr = lane & 15, fq = lane >> 4;
  const int bh = blockIdx.x >> 6, ch = blockIdx.x & 63;
  const int b = bh >> 2, hh = bh & 3;
  const int c0 = ch * CH;
  const u16* qbase = q + (size_t)b * Lseq * DK + hh * DQH;
  const u16* kbase = k + (size_t)b * Lseq * DK + hh * DQH;
  u16*       vbase = v + (size_t)b * Lseq * DV + hh * DVH;
  const float* bbase = beta + (size_t)bh * Lseq;
  u16* Wrow  = Wout  + ((size_t)bh * Lseq + c0) * DQH;
  u16* QKrow = QKout + ((size_t)bh * Lseq + c0) * CH;

  if (tid < 64) Bc[tid] = bbase[c0 + tid];
  lds_barrier();

  {   // G = K K^T, QKt = Q K^T via MFMA
    const int m0 = wid * 16;
    f32x4 accG[4], accQ[4];
#pragma unroll
    for (int ni = 0; ni < 4; ++ni) {
      accG[ni] = {0.f, 0.f, 0.f, 0.f};
      accQ[ni] = {0.f, 0.f, 0.f, 0.f};
    }
#pragma unroll
    for (int kt = 0; kt < 4; ++kt) {
      bf16x8 afk = *(const bf16x8*)&kbase[(size_t)(c0 + m0 + fr) * DK + kt * 32 + fq * 8];
      bf16x8 afq = *(const bf16x8*)&qbase[(size_t)(c0 + m0 + fr) * DK + kt * 32 + fq * 8];
#pragma unroll
      for (int ni = 0; ni < 4; ++ni) {
        bf16x8 bfk = *(const bf16x8*)&kbase[(size_t)(c0 + ni * 16 + fr) * DK + kt * 32 + fq * 8];
        accG[ni] = __builtin_amdgcn_mfma_f32_16x16x32_bf16(afk, bfk, accG[ni], 0, 0, 0);
        accQ[ni] = __builtin_amdgcn_mfma_f32_16x16x32_bf16(afq, bfk, accQ[ni], 0, 0, 0);
      }
    }
#pragma unroll
    for (int ni = 0; ni < 4; ++ni)
#pragma unroll
      for (int i = 0; i < 4; ++i) {
        int row = m0 + fq * 4 + i, col = ni * 16 + fr;
        float br = Bc[row];
        Am[row][col] = (col < row) ? br * accG[ni][i] : 0.f;
        QKrow[(size_t)row * CH + col] = f2b((col <= row) ? accQ[ni][i] : 0.f);
      }
  }
  lds_barrier();

  for (int p = 0; p < 6; ++p) {
    if (p < 2) {
      const int dbase = p * 64;
      for (int idx = tid; idx < 64 * 64; idx += 256) {
        int r = idx >> 6, d = idx & 63;
        R[r][d] = Bc[r] * b2f(kbase[(size_t)(c0 + r) * DK + dbase + d]);
      }
    } else {
      const int cbase = (p - 2) * 64;
      for (int idx = tid; idx < 64 * 64; idx += 256) {
        int r = idx >> 6, j = idx & 63;
        R[r][j] = Bc[r] * b2f(vbase[(size_t)(c0 + r) * DV + cbase + j]);
      }
    }
    lds_barrier();
    for (int rb = 0; rb < 4; ++rb) {   // blocked forward substitution
      if (rb > 0) {
        const int c = tid & 63, g = tid >> 6;
        const int R0 = rb * 16, row = R0 + g * 4;
        float s0 = 0, s1 = 0, s2 = 0, s3 = 0;
        for (int m = 0; m < R0; ++m) {
          float uv = R[m][c];
          s0 = fmaf(Am[row + 0][m], uv, s0);
          s1 = fmaf(Am[row + 1][m], uv, s1);
          s2 = fmaf(Am[row + 2][m], uv, s2);
          s3 = fmaf(Am[row + 3][m], uv, s3);
        }
        R[row + 0][c] -= s0; R[row + 1][c] -= s1;
        R[row + 2][c] -= s2; R[row + 3][c] -= s3;
      }
      lds_barrier();
      if (tid < 64) {
        const int c = tid;
        for (int i = 1; i < 16; ++i) {
          const int row = rb * 16 + i;
          float s = R[row][c];
          for (int m = 0; m < i; ++m)
            s = fmaf(-Am[row][rb * 16 + m], R[rb * 16 + m][c], s);
          R[row][c] = s;
        }
      }
      lds_barrier();
    }
    if (p < 2) {
      const int dbase = p * 64;
      for (int idx = tid; idx < 64 * 64; idx += 256) {
        int r = idx >> 6, d = idx & 63;
        Wrow[(size_t)r * DQH + dbase + d] = f2b(-R[r][d]);   // NEGATED
      }
    } else {
      const int cbase = (p - 2) * 64;
      for (int idx = tid; idx < 64 * 64; idx += 256) {
        int r = idx >> 6, j = idx & 63;
        vbase[(size_t)(c0 + r) * DV + cbase + j] = f2b(R[r][j]);
      }
    }
    lds_barrier();
  }
}

// ---- 5b. delta scan (MFMA, prefetch, LDS-only barriers, split acc chains) ----
__global__ __launch_bounds__(512) void delta_scan_kernel(
    const u16* __restrict__ q, const u16* __restrict__ k,
    const u16* __restrict__ Wb, const u16* __restrict__ QKb, u16* uo) {
  __shared__ alignas(16) u16 Kt[128][72];
  __shared__ alignas(16) u16 Sbt_hi[16][136];
  __shared__ alignas(16) u16 Sbt_lo[16][136];
  __shared__ alignas(16) u16 Ubt[16][72];
  const int tid = threadIdx.x;
  const int wid = tid >> 6, lane = tid & 63;
  const int fr = lane & 15, fq = lane >> 4;
  const int m0w = 16 * (wid & 3);
  // XCD locality: all 16 vblk-blocks of one bh land on XCD bh%8
  const int bh = blockIdx.x & 15, vblk = blockIdx.x >> 4;
  const int b = bh >> 2, hh = bh & 3;
  const u16* qbase = q + (size_t)b * Lseq * DK + hh * DQH;
  const u16* kbase = k + (size_t)b * Lseq * DK + hh * DQH;
  const u16* Wbase = Wb + (size_t)bh * Lseq * DQH;
  const u16* QKbase = QKb + (size_t)bh * Lseq * CH;
  u16* uobase = uo + (size_t)b * Lseq * DV + hh * DVH + vblk * 16;

  for (int i = tid; i < 16 * 136; i += 512) {
    (&Sbt_hi[0][0])[i] = 0; (&Sbt_lo[0][0])[i] = 0;
  }
  f32x4 Sfrag = {0.f, 0.f, 0.f, 0.f};

  const int kr0 = tid & 63, kd0 = (tid >> 6) << 3;
  const int kr1 = (tid + 512) & 63, kd1 = ((tid + 512) >> 6) << 3;

  us8 kpre0 = *(const us8*)&kbase[(size_t)kr0 * DK + kd0];
  us8 kpre1 = *(const us8*)&kbase[(size_t)kr1 * DK + kd1];
  bf16x8 fpre[4];
  bf16x8 qkpre0 = {}, qkpre1 = {};
  ushort4 u0pre = {};
  if (wid < 4) {
    const u16* wp = Wbase + (size_t)(m0w + fr) * DQH + fq * 8;
#pragma unroll
    for (int kt = 0; kt < 4; ++kt) fpre[kt] = *(const bf16x8*)&wp[kt * 32];
    const u16* up = uobase + (size_t)(m0w + fq * 4) * DV + fr;
    u0pre.x = up[0]; u0pre.y = up[(size_t)DV];
    u0pre.z = up[(size_t)2 * DV]; u0pre.w = up[(size_t)3 * DV];
  } else {
    const u16* qp = qbase + (size_t)(m0w + fr) * DK + fq * 8;
#pragma unroll
    for (int kt = 0; kt < 4; ++kt) fpre[kt] = *(const bf16x8*)&qp[kt * 32];
    const u16* qkp = QKbase + (size_t)(m0w + fr) * CH + fq * 8;
    qkpre0 = *(const bf16x8*)&qkp[0];
    qkpre1 = *(const bf16x8*)&qkp[32];
  }
  __syncthreads();

  for (int c0 = 0; c0 < Lseq; c0 += CH) {
#pragma unroll
    for (int j = 0; j < 8; ++j) Kt[kd0 + j][kr0] = kpre0.u[j];
#pragma unroll
    for (int j = 0; j < 8; ++j) Kt[kd1 + j][kr1] = kpre1.u[j];

    bf16x8 fcur[4];
#pragma unroll
    for (int kt = 0; kt < 4; ++kt) fcur[kt] = fpre[kt];
    bf16x8 qkc0 = qkpre0, qkc1 = qkpre1;
    ushort4 u0c = u0pre;

    if (c0 + CH < Lseq) {
      const int cn = c0 + CH;
      kpre0 = *(const us8*)&kbase[(size_t)(cn + kr0) * DK + kd0];
      kpre1 = *(const us8*)&kbase[(size_t)(cn + kr1) * DK + kd1];
      if (wid < 4) {
        const u16* wp = Wbase + (size_t)(cn + m0w + fr) * DQH + fq * 8;
#pragma unroll
        for (int kt = 0; kt < 4; ++kt) fpre[kt] = *(const bf16x8*)&wp[kt * 32];
        const u16* up = uobase + (size_t)(cn + m0w + fq * 4) * DV + fr;
        u0pre.x = up[0]; u0pre.y = up[(size_t)DV];
        u0pre.z = up[(size_t)2 * DV]; u0pre.w = up[(size_t)3 * DV];
      } else {
        const u16* qp = qbase + (size_t)(cn + m0w + fr) * DK + fq * 8;
#pragma unroll
        for (int kt = 0; kt < 4; ++kt) fpre[kt] = *(const bf16x8*)&qp[kt * 32];
        const u16* qkp = QKbase + (size_t)(cn + m0w + fr) * CH + fq * 8;
        qkpre0 = *(const bf16x8*)&qkp[0];
        qkpre1 = *(const bf16x8*)&qkp[32];
      }
    }

    f32x4 acc, accB;
    if (wid < 4) {
      // phase1: U = U0 + Wneg·(S_hi + S_lo), two independent chains
      acc[0] = b2f(u0c.x); acc[1] = b2f(u0c.y);
      acc[2] = b2f(u0c.z); acc[3] = b2f(u0c.w);
      accB = (f32x4){0.f, 0.f, 0.f, 0.f};
#pragma unroll
      for (int kt = 0; kt < 2; ++kt) {
        bf16x8 sh = *(const bf16x8*)&Sbt_hi[fr][kt * 32 + fq * 8];
        bf16x8 sl = *(const bf16x8*)&Sbt_lo[fr][kt * 32 + fq * 8];
        acc = __builtin_amdgcn_mfma_f32_16x16x32_bf16(fcur[kt], sh, acc, 0, 0, 0);
        acc = __builtin_amdgcn_mfma_f32_16x16x32_bf16(fcur[kt], sl, acc, 0, 0, 0);
      }
#pragma unroll
      for (int kt = 2; kt < 4; ++kt) {
        bf16x8 sh = *(const bf16x8*)&Sbt_hi[fr][kt * 32 + fq * 8];
        bf16x8 sl = *(const bf16x8*)&Sbt_lo[fr][kt * 32 + fq * 8];
        accB = __builtin_amdgcn_mfma_f32_16x16x32_bf16(fcur[kt], sh, accB, 0, 0, 0);
        accB = __builtin_amdgcn_mfma_f32_16x16x32_bf16(fcur[kt], sl, accB, 0, 0, 0);
      }
      ushort4 ub = {f2b(acc[0] + accB[0]), f2b(acc[1] + accB[1]),
                    f2b(acc[2] + accB[2]), f2b(acc[3] + accB[3])};
      *(ushort4*)&Ubt[fr][m0w + fq * 4] = ub;
    } else {
      // phase2a: O = Q·S_hi, two independent chains
      acc = (f32x4){0.f, 0.f, 0.f, 0.f};
      accB = (f32x4){0.f, 0.f, 0.f, 0.f};
#pragma unroll
      for (int kt = 0; kt < 2; ++kt) {
        bf16x8 sh = *(const bf16x8*)&Sbt_hi[fr][kt * 32 + fq * 8];
        acc = __builtin_amdgcn_mfma_f32_16x16x32_bf16(fcur[kt], sh, acc, 0, 0, 0);
      }
#pragma unroll
      for (int kt = 2; kt < 4; ++kt) {
        bf16x8 sh = *(const bf16x8*)&Sbt_hi[fr][kt * 32 + fq * 8];
        accB = __builtin_amdgcn_mfma_f32_16x16x32_bf16(fcur[kt], sh, accB, 0, 0, 0);
      }
    }
    lds_barrier();   // Ubt + Kt visible; global ops stay in flight

    if (wid >= 4) {
      bf16x8 uf0 = *(const bf16x8*)&Ubt[fr][fq * 8];
      bf16x8 uf1 = *(const bf16x8*)&Ubt[fr][32 + fq * 8];
      acc  = __builtin_amdgcn_mfma_f32_16x16x32_bf16(qkc0, uf0, acc, 0, 0, 0);
      accB = __builtin_amdgcn_mfma_f32_16x16x32_bf16(qkc1, uf1, accB, 0, 0, 0);
      u16* op = uobase + (size_t)(c0 + m0w + fq * 4) * DV + fr;
      op[0] = f2b(acc[0] + accB[0]);
      op[(size_t)DV] = f2b(acc[1] + accB[1]);
      op[(size_t)2 * DV] = f2b(acc[2] + accB[2]);
      op[(size_t)3 * DV] = f2b(acc[3] + accB[3]);
    }
#pragma unroll
    for (int kt = 0; kt < 2; ++kt) {
      bf16x8 kf = *(const bf16x8*)&Kt[16 * wid + fr][kt * 32 + fq * 8];
      bf16x8 uf = *(const bf16x8*)&Ubt[fr][kt * 32 + fq * 8];
      Sfrag = __builtin_amdgcn_mfma_f32_16x16x32_bf16(kf, uf, Sfrag, 0, 0, 0);
    }
    ushort4 shv, slv;
#pragma unroll
    for (int i = 0; i < 4; ++i) {
      float s = Sfrag[i];
      u16 hpart = f2b(s);
      ((u16*)&shv)[i] = hpart;
      ((u16*)&slv)[i] = f2b(s - b2f(hpart));
    }
    *(ushort4*)&Sbt_hi[fr][16 * wid + fq * 4] = shv;
    *(ushort4*)&Sbt_lo[fr][16 * wid + fq * 4] = slv;
    lds_barrier();   // Sbt ready; Kt/Ubt free
  }
}

// ---- 6. gate ----
__global__ __launch_bounds__(256) void gate_kernel(
    const u16* og, const u16* __restrict__ g,
    const float* __restrict__ nw, u16* out) {
  int idx = blockIdx.x * 4 + (threadIdx.x >> 6), lane = threadIdx.x & 63;
  size_t base = (size_t)(idx >> 2) * DV + (size_t)(idx & 3) * DVH + (size_t)lane * 4;
  ushort4 o4 = *(const ushort4*)&og[base];
  float ox = b2f(o4.x), oy = b2f(o4.y), oz = b2f(o4.z), ow = b2f(o4.w);
  float ss = ox * ox + oy * oy + oz * oz + ow * ow;
#pragma unroll
  for (int off = 32; off; off >>= 1) ss += __shfl_xor(ss, off);
  float r = 1.f / sqrtf(ss * (1.f / DVH) + 1e-5f);
  ushort4 g4 = *(const ushort4*)&g[base];
  float gx = b2f(g4.x), gy = b2f(g4.y), gz = b2f(g4.z), gw = b2f(g4.w);
  float4 wv = *(const float4*)&nw[lane * 4];
  ushort4 res;
  res.x = f2b(ox * r * wv.x * (gx * sig_(gx)));
  res.y = f2b(oy * r * wv.y * (gy * sig_(gy)));
  res.z = f2b(oz * r * wv.z * (gz * sig_(gz)));
  res.w = f2b(ow * r * wv.w * (gw * sig_(gw)));
  *(ushort4*)&out[base] = res;
}

// ---- host ----
extern "C" void kernel_launch(void* const* d_in, const int* in_sizes, int n_in,
                              void* d_out, int out_size, void* d_ws, size_t ws_size,
                              hipStream_t stream) {
  (void)in_sizes; (void)n_in; (void)out_size;
  const float* x  = (const float*)d_in[0];
  const float* cw = (const float*)d_in[1];
  const float* Wq = (const float*)d_in[2];
  const float* Wk = (const float*)d_in[3];
  const float* Wv = (const float*)d_in[4];
  const float* Wb = (const float*)d_in[5];
  const float* Wg = (const float*)d_in[6];
  const float* nw = (const float*)d_in[7];
  const float* Wo = (const float*)d_in[8];
  float* out = (float*)d_out;   // f32 output

  u16* hb = (u16*)d_ws;                       // ROWS*Dm  bf16
  u16* qb = hb + (size_t)ROWS * Dm;           // ROWS*DK
  u16* kb = qb + (size_t)ROWS * DK;           // ROWS*DK
  u16* vb = kb + (size_t)ROWS * DK;           // ROWS*DV  (v -> U0 -> O; gate in-place)
  float* bbuf = (float*)(vb + (size_t)ROWS * DV);   // ROWS*H f32
  u16* Wbuf  = (u16*)(bbuf + (size_t)ROWS * H);     // 16*Lseq*DQH bf16 (negated)
  u16* QKbuf = Wbuf + (size_t)16 * Lseq * DQH;      // 16*Lseq*CH  bf16
  u16* wq16 = QKbuf + (size_t)16 * Lseq * CH;       // bf16 weights, TRANSPOSED [N][K]
  u16* wk16 = wq16 + (size_t)Dm * DK;
  u16* wv16 = wk16 + (size_t)Dm * DK;
  u16* wg16 = wv16 + (size_t)Dm * DV;
  u16* wo16 = wg16 + (size_t)Dm * DV;
  u16* gb = qb;                               // g reuses q+k region after scan

  const size_t need = (size_t)ROWS * (Dm + DK + DK + DV) * 2 + (size_t)ROWS * H * 4
                    + (size_t)16 * Lseq * (DQH + CH) * 2
                    + ((size_t)Dm * (DK * 2 + DV * 3)) * 2;
  if (ws_size < need) {
    ws_sentinel_kernel<<<1, 1, 0, stream>>>(out, (float)ws_size);
    return;
  }

  // weight convert + transpose: in [K][N] f32 -> out [N][K] bf16
  cvt_t_kernel<<<dim3(DK / 64, Dm / 32), 256, 0, stream>>>(Wq, wq16, DK, Dm);
  cvt_t_kernel<<<dim3(DK / 64, Dm / 32), 256, 0, stream>>>(Wk, wk16, DK, Dm);
  cvt_t_kernel<<<dim3(DV / 64, Dm / 32), 256, 0, stream>>>(Wv, wv16, DV, Dm);
  cvt_t_kernel<<<dim3(DV / 64, Dm / 32), 256, 0, stream>>>(Wg, wg16, DV, Dm);
  cvt_t_kernel<<<dim3(Dm / 64, DV / 32), 256, 0, stream>>>(Wo, wo16, Dm, DV);

  conv_silu_kernel<<<ROWS * Dm / 256, 256, 0, stream>>>(x, cw, hb);

  // q/k with fused l2norm (128-col tile == one head)
  gemm_mfma_kernel<2><<<(DK / 128) * (ROWS / 128), 256, 0, stream>>>(hb, wq16, qb, ROWS, DK, Dm);
  gemm_mfma_kernel<2><<<(DK / 128) * (ROWS / 128), 256, 0, stream>>>(hb, wk16, kb, ROWS, DK, Dm);
  gemm_mfma_kernel<0><<<(DV / 128) * (ROWS / 128), 256, 0, stream>>>(hb, wv16, vb, ROWS, DV, Dm);
  beta_kernel<<<ROWS / 4, 256, 0, stream>>>(hb, Wb, bbuf);

  delta_prep_kernel<<<1024, 256, 0, stream>>>(qb, kb, vb, bbuf, Wbuf, QKbuf);
  delta_scan_kernel<<<256, 512, 0, stream>>>(qb, kb, Wbuf, QKbuf, vb);

  gemm_mfma_kernel<0><<<(DV / 128) * (ROWS / 128), 256, 0, stream>>>(hb, wg16, gb, ROWS, DV, Dm);
  gate_kernel<<<ROWS * H / 4, 256, 0, stream>>>(vb, gb, nw, vb);

  gemm_mfma_kernel<1><<<(Dm / 128) * (ROWS / 128), 256, 0, stream>>>(vb, wo16, out, ROWS, Dm, DV);
}